// Round 4
// baseline (626.953 us; speedup 1.0000x reference)
//
#include <hip/hip_runtime.h>
#include <hip/hip_bf16.h>

typedef unsigned short u16;
typedef unsigned int u32;
typedef __attribute__((ext_vector_type(8))) short bf16x8;
typedef __attribute__((ext_vector_type(4))) float f32x4;

#define T_DIM 2048
#define B_DIM 32
#define H_DIM 512

__device__ inline unsigned pack2(float a, float b) {
  union { __hip_bfloat162 h2; unsigned u; } c;
  c.h2 = __float22bfloat162_rn(make_float2(a, b));
  return c.u;
}

// Precompute: r[b*512+h] = hidden[b]·W1[h] + b_attn[h]; u[h] = W3[h]·W_cov;
// W2bf = bf16(W2) in FRAGMENT-MAJOR layout (unchanged, harness-verified).
__global__ __launch_bounds__(256) void prep_kernel(
    const float* __restrict__ hidden, const float* __restrict__ W_attn,
    const float* __restrict__ b_attn, const float* __restrict__ W_cov,
    u16* __restrict__ W2bf, float* __restrict__ r, float* __restrict__ u)
{
  const int tid = blockIdx.x * 256 + threadIdx.x;  // 0..65535
  const int pair = tid >> 2;                       // b*512 + h
  const int kq = tid & 3;
  const int b = pair >> 9, h = pair & 511;

  {
    const float* hid = hidden + b * 512 + kq * 128;
    const float* w1 = W_attn + (size_t)h * 1536 + kq * 128;
    float acc = 0.f;
    #pragma unroll 8
    for (int k = 0; k < 128; k += 4) {
      float4 x = *(const float4*)(hid + k);
      float4 w = *(const float4*)(w1 + k);
      acc += x.x * w.x + x.y * w.y + x.z * w.z + x.w * w.w;
    }
    acc += __shfl_xor(acc, 1);
    acc += __shfl_xor(acc, 2);
    if (kq == 0) r[pair] = acc + b_attn[h];
  }

  {
    int j0 = tid * 4;
    int hh = j0 >> 9, kk = j0 & 511;
    float4 w = *(const float4*)(W_attn + (size_t)hh * 1536 + 512 + kk);
    uint2 p;
    p.x = pack2(w.x, w.y);
    p.y = pack2(w.z, w.w);
    int f = hh >> 4, c = hh & 15;
    int ks = kk >> 5, quad = (kk >> 3) & 3, e = kk & 7;   // e in {0,4}
    *(uint2*)(W2bf + (size_t)((f * 16 + ks) * 64 + quad * 16 + c) * 8 + e) = p;
  }

  if (tid < 2048) {
    int h3 = tid >> 2;
    const float* w3 = W_attn + (size_t)h3 * 1536 + 1024 + kq * 128;
    const float* wc = W_cov + kq * 128;
    float su = 0.f;
    #pragma unroll 8
    for (int k = 0; k < 128; k += 4) {
      float4 a = *(const float4*)(w3 + k);
      float4 c = *(const float4*)(wc + k);
      su += a.x * c.x + a.y * c.y + a.z * c.z + a.w * c.w;
    }
    su += __shfl_xor(su, 1);
    su += __shfl_xor(su, 2);
    if (kq == 0) u[h3] = su;
  }
}

// v5: 512 persistent blocks (512 thr, 8 waves), each owns 4 consecutive t-tiles
// (32 rows each). A-path back to bf16-in-LDS (r0's measured-best: half the
// ds_read bytes of fp32). Cross-tile software pipeline (T14): issue tile t+1's
// 8 float4 A-loads BEFORE tile t's K-loop (sched_barrier pins them there);
// cvt + swizzled ds_write AFTER the epilogue. The barrier's forced vmcnt(0)
// lands ~4000 cycles after issue -> HBM latency + stage fully hidden under
// compute; HBM streams continuously. B frags: fragment-major W2bf from L2,
// register double-buffered 2 deep (verified r2). Epilogue: final-score
// reduction via red[] (verified r2) -> part holds score[b][t].
__global__ __launch_bounds__(512, 4) void gemm_score(
    const float* __restrict__ enc, const u16* __restrict__ W2bf,
    const float* __restrict__ r, const float* __restrict__ u,
    const float* __restrict__ vv, const float* __restrict__ cov,
    float* __restrict__ part)
{
  const int blk = blockIdx.x;          // owns t = blk*4 .. blk*4+3
  const int tid = threadIdx.x;
  const int lane = tid & 63;
  const int w = tid >> 6;              // wave 0..7 -> n-slab [w*64, w*64+64)
  const int quad = lane >> 4, col = lane & 15;

  __shared__ u16 As[2][32 * 512];      // 2 x 32 KB bf16, [row][k], 16B-group XOR swizzle
  __shared__ float red[256];           // cross-wave score reduce

  const u16* bbase = W2bf + (size_t)w * 32768 + lane * 8;

  // Stage geometry: wave w covers rows w*4..w*4+3; lane -> (row, 4 granule-chunks)
  const int srow = w * 4 + (lane >> 4);     // 0..31
  const int g16 = lane & 15;

  // ---- Prologue: stage tile 0 (load -> cvt -> swizzled LDS write) ----
  float4 sb[8];
  {
    const float* gb = enc + ((size_t)blk * 4 * 32 + srow) * 512;
    #pragma unroll
    for (int q = 0; q < 4; ++q) {
      int G = g16 + 16 * q;                  // bf16 16B-granule 0..63
      sb[q * 2]     = *(const float4*)(gb + G * 8);
      sb[q * 2 + 1] = *(const float4*)(gb + G * 8 + 4);
    }
  }
  #pragma unroll
  for (int q = 0; q < 4; ++q) {
    int G = g16 + 16 * q;
    uint4 p;
    p.x = pack2(sb[q * 2].x,     sb[q * 2].y);
    p.y = pack2(sb[q * 2].z,     sb[q * 2].w);
    p.z = pack2(sb[q * 2 + 1].x, sb[q * 2 + 1].y);
    p.w = pack2(sb[q * 2 + 1].z, sb[q * 2 + 1].w);
    *(uint4*)&As[0][srow * 512 + (G ^ (srow & 7)) * 8] = p;   // verified r0 swizzle pair
  }
  __syncthreads();

  float uj[4], vj[4];
  #pragma unroll
  for (int j = 0; j < 4; ++j) {
    int gh = w * 64 + j * 16 + col;
    uj[j] = u[gh];
    vj[j] = vv[gh];
  }

  #pragma unroll 1
  for (int tl = 0; tl < 4; ++tl) {
    const int t = blk * 4 + tl;
    const int cur = tl & 1;

    // ---- Issue tile t+1 A-loads (in flight under the whole K-loop) ----
    if (tl < 3) {
      const float* gb = enc + ((size_t)(t + 1) * 32 + srow) * 512;
      #pragma unroll
      for (int q = 0; q < 4; ++q) {
        int G = g16 + 16 * q;
        sb[q * 2]     = *(const float4*)(gb + G * 8);
        sb[q * 2 + 1] = *(const float4*)(gb + G * 8 + 4);
      }
    }
    __builtin_amdgcn_sched_barrier(0);   // pin load-issue above the K-loop

    // ---- K-loop: bf16 A frags from LDS, B 2-deep from L2, no barriers ----
    bf16x8 bb[2][4];
    #pragma unroll
    for (int j = 0; j < 4; ++j) {
      bb[0][j] = *(const bf16x8*)(bbase + j * 8192);
      bb[1][j] = *(const bf16x8*)(bbase + j * 8192 + 512);
    }
    f32x4 acc[2][4] = {};
    #pragma unroll
    for (int ks = 0; ks < 16; ++ks) {
      #pragma unroll
      for (int i = 0; i < 2; ++i) {
        int row = i * 16 + col;
        bf16x8 af = *(const bf16x8*)&As[cur][row * 512 + ((ks * 4 + quad) ^ (col & 7)) * 8];
        #pragma unroll
        for (int j = 0; j < 4; ++j)
          acc[i][j] = __builtin_amdgcn_mfma_f32_16x16x32_bf16(af, bb[ks & 1][j], acc[i][j], 0, 0, 0);
      }
      if (ks < 14) {
        #pragma unroll
        for (int j = 0; j < 4; ++j)
          bb[ks & 1][j] = *(const bf16x8*)(bbase + j * 8192 + (ks + 2) * 512);
      }
    }

    // ---- Epilogue: e = relu(acc + r + cov*u); s = e·v; wave + block reduce ----
    #pragma unroll
    for (int i = 0; i < 2; ++i) {
      #pragma unroll
      for (int reg = 0; reg < 4; ++reg) {
        int bl = i * 16 + quad * 4 + reg;        // C/D layout: row = quad*4 + reg
        float cv = cov[bl * 2048 + t];
        float s = 0.f;
        #pragma unroll
        for (int j = 0; j < 4; ++j) {
          float rv = r[bl * 512 + w * 64 + j * 16 + col];
          float e = acc[i][j][reg] + rv + cv * uj[j];
          e = fmaxf(e, 0.f);
          s += e * vj[j];
        }
        s += __shfl_xor(s, 1);
        s += __shfl_xor(s, 2);
        s += __shfl_xor(s, 4);
        s += __shfl_xor(s, 8);
        if (col == 0) red[w * 32 + bl] = s;
      }
    }
    __syncthreads();                    // red ready; A-loads drained (hidden)
    if (tid < 32) {
      float s = 0.f;
      #pragma unroll
      for (int p = 0; p < 8; ++p) s += red[p * 32 + tid];
      part[(size_t)tid * 2048 + t] = s; // final score[b][t]
    }

    // ---- Write-late: cvt + swizzled LDS store of tile t+1 into buf cur^1 ----
    if (tl < 3) {
      #pragma unroll
      for (int q = 0; q < 4; ++q) {
        int G = g16 + 16 * q;
        uint4 p;
        p.x = pack2(sb[q * 2].x,     sb[q * 2].y);
        p.y = pack2(sb[q * 2].z,     sb[q * 2].w);
        p.z = pack2(sb[q * 2 + 1].x, sb[q * 2 + 1].y);
        p.w = pack2(sb[q * 2 + 1].z, sb[q * 2 + 1].w);
        *(uint4*)&As[cur ^ 1][srow * 512 + (G ^ (srow & 7)) * 8] = p;
      }
    }
    __syncthreads();                    // buf published; also guards red reuse
  }
}

// Softmax over T per batch + coverage update. 32 blocks x 256 threads.
__global__ __launch_bounds__(256) void softmax_kernel(
    const float* __restrict__ part, const float* __restrict__ cov, float* __restrict__ out)
{
  const int b = blockIdx.x;
  const int tid = threadIdx.x;
  const int lane = tid & 63, wid = tid >> 6;
  __shared__ float red[4];
  float loc[8];
  float lmax = -3.4e38f;
  #pragma unroll
  for (int i = 0; i < 8; ++i) {
    int t = tid + i * 256;
    float s = part[(size_t)b * 2048 + t];
    loc[i] = s;
    lmax = fmaxf(lmax, s);
  }
  #pragma unroll
  for (int o = 32; o; o >>= 1) lmax = fmaxf(lmax, __shfl_xor(lmax, o));
  if (lane == 0) red[wid] = lmax;
  __syncthreads();
  float bmax = fmaxf(fmaxf(red[0], red[1]), fmaxf(red[2], red[3]));
  __syncthreads();
  float lsum = 0.f;
  #pragma unroll
  for (int i = 0; i < 8; ++i) { loc[i] = __expf(loc[i] - bmax); lsum += loc[i]; }
  #pragma unroll
  for (int o = 32; o; o >>= 1) lsum += __shfl_xor(lsum, o);
  if (lane == 0) red[wid] = lsum;
  __syncthreads();
  float inv = 1.0f / (red[0] + red[1] + red[2] + red[3]);
  #pragma unroll
  for (int i = 0; i < 8; ++i) {
    int t = tid + i * 256;
    float a = loc[i] * inv;
    out[b * 2048 + t] = a;                               // attn_weights [B,1,T]
    out[65536 + b * 2048 + t] = cov[b * 2048 + t] + a;   // coverage_new [B,T]
  }
}

extern "C" void kernel_launch(void* const* d_in, const int* in_sizes, int n_in,
                              void* d_out, int out_size, void* d_ws, size_t ws_size,
                              hipStream_t stream) {
  const float* hidden = (const float*)d_in[0];   // [1,B,H]
  const float* enc    = (const float*)d_in[1];   // [T,B,H]
  const float* cov    = (const float*)d_in[2];   // [B,T]
  const float* W_attn = (const float*)d_in[3];   // [H,3H]
  const float* b_attn = (const float*)d_in[4];   // [H]
  const float* vv     = (const float*)d_in[5];   // [H]
  const float* W_cov  = (const float*)d_in[6];   // [H,1]
  float* out = (float*)d_out;

  u16* W2bf = (u16*)d_ws;                              // 512 KB (fragment-major)
  float* r  = (float*)((char*)d_ws + 512 * 1024);      // 64 KB
  float* u  = r + 32 * 512;                            // 2 KB
  float* part = u + 512;                               // 32*2048*4 = 256 KB (final scores)

  hipLaunchKernelGGL(prep_kernel, dim3(256), dim3(256), 0, stream,
                     hidden, W_attn, b_attn, W_cov, W2bf, r, u);
  hipLaunchKernelGGL(gemm_score, dim3(512), dim3(512), 0, stream,
                     enc, W2bf, r, u, vv, cov, part);
  hipLaunchKernelGGL(softmax_kernel, dim3(32), dim3(256), 0, stream,
                     part, cov, out);
}

// Round 5
// 433.437 us; speedup vs baseline: 1.4465x; 1.4465x over previous
//
#include <hip/hip_runtime.h>
#include <hip/hip_bf16.h>

typedef unsigned short u16;
typedef unsigned int u32;
typedef __attribute__((ext_vector_type(8))) short bf16x8;
typedef __attribute__((ext_vector_type(4))) float f32x4;

#define T_DIM 2048
#define B_DIM 32
#define H_DIM 512

__device__ inline unsigned pack2(float a, float b) {
  union { __hip_bfloat162 h2; unsigned u; } c;
  c.h2 = __float22bfloat162_rn(make_float2(a, b));
  return c.u;
}

// Precompute: r[b*512+h] = hidden[b]·W1[h] + b_attn[h]; u[h] = W3[h]·W_cov;
// W2bf = bf16(W2) in FRAGMENT-MAJOR layout (unchanged, harness-verified).
__global__ __launch_bounds__(256) void prep_kernel(
    const float* __restrict__ hidden, const float* __restrict__ W_attn,
    const float* __restrict__ b_attn, const float* __restrict__ W_cov,
    u16* __restrict__ W2bf, float* __restrict__ r, float* __restrict__ u)
{
  const int tid = blockIdx.x * 256 + threadIdx.x;  // 0..65535
  const int pair = tid >> 2;                       // b*512 + h
  const int kq = tid & 3;
  const int b = pair >> 9, h = pair & 511;

  {
    const float* hid = hidden + b * 512 + kq * 128;
    const float* w1 = W_attn + (size_t)h * 1536 + kq * 128;
    float acc = 0.f;
    #pragma unroll 8
    for (int k = 0; k < 128; k += 4) {
      float4 x = *(const float4*)(hid + k);
      float4 w = *(const float4*)(w1 + k);
      acc += x.x * w.x + x.y * w.y + x.z * w.z + x.w * w.w;
    }
    acc += __shfl_xor(acc, 1);
    acc += __shfl_xor(acc, 2);
    if (kq == 0) r[pair] = acc + b_attn[h];
  }

  {
    int j0 = tid * 4;
    int hh = j0 >> 9, kk = j0 & 511;
    float4 w = *(const float4*)(W_attn + (size_t)hh * 1536 + 512 + kk);
    uint2 p;
    p.x = pack2(w.x, w.y);
    p.y = pack2(w.z, w.w);
    int f = hh >> 4, c = hh & 15;
    int ks = kk >> 5, quad = (kk >> 3) & 3, e = kk & 7;   // e in {0,4}
    *(uint2*)(W2bf + (size_t)((f * 16 + ks) * 64 + quad * 16 + c) * 8 + e) = p;
  }

  if (tid < 2048) {
    int h3 = tid >> 2;
    const float* w3 = W_attn + (size_t)h3 * 1536 + 1024 + kq * 128;
    const float* wc = W_cov + kq * 128;
    float su = 0.f;
    #pragma unroll 8
    for (int k = 0; k < 128; k += 4) {
      float4 a = *(const float4*)(w3 + k);
      float4 c = *(const float4*)(wc + k);
      su += a.x * c.x + a.y * c.y + a.z * c.z + a.w * c.w;
    }
    su += __shfl_xor(su, 1);
    su += __shfl_xor(su, 2);
    if (kq == 0) u[h3] = su;
  }
}

// v6: producer/consumer wave specialization. 256 persistent blocks (1/CU,
// 128KB LDS ring), 768 threads = 12 waves. Waves 8-11: producers — stream
// enc (fp32) -> cvt bf16 -> swizzled LDS ring (4 slots x 32 rows), 16
// independent float4 loads in flight each, continuously, across the block's
// 8 tiles. Their vmcnt queue is NEVER drained by compute waits. Waves 0-7:
// consumers — spin on LDS fill flags (s_sleep), then the verified r0 K-loop:
// A frags from swizzled LDS, B frags 2-deep from L2-resident fragment-major
// W2bf (consumer vmcnt tracks ONLY fast L2 loads — no HBM poisoning).
// No __syncthreads in steady state; monotone fill/done counters, 4-deep ring.
// r-slice preloaded to 32 regs (kills 134MB/dispatch hidden L2 re-read).
__global__ __launch_bounds__(768, 3) void gemm_score(
    const float* __restrict__ enc, const u16* __restrict__ W2bf,
    const float* __restrict__ r, const float* __restrict__ u,
    const float* __restrict__ vv, const float* __restrict__ cov,
    float* __restrict__ part)
{
  const int blk = blockIdx.x;            // owns t = blk*8 .. blk*8+7
  const int tid = threadIdx.x;
  const int lane = tid & 63;
  const int w = tid >> 6;                // 0..11

  __shared__ u16 As[4][32 * 512];        // 128 KB ring: 4 slots x 32KB bf16
  __shared__ int fill[4];                // producer-wave completions per slot
  __shared__ int done[4];                // consumer-wave completions per slot

  if (tid < 4) { fill[tid] = 0; done[tid] = 0; }
  __syncthreads();                       // once, all 12 waves — flag init only

  volatile int* vfill = (volatile int*)fill;
  volatile int* vdone = (volatile int*)done;

  if (w >= 8) {
    // ---------------- producers: waves 8-11 ----------------
    const int pw = w - 8;                     // 0..3
    const int row = pw * 8 + (lane >> 3);     // 0..31
    const int g0 = lane & 7;                  // base 16B-granule
    #pragma unroll 1
    for (int tl = 0; tl < 8; ++tl) {
      const int s = tl & 3, n = tl >> 2;
      if (n >= 1) {                           // slot reuse: wait consumers done
        while (vdone[s] < 8 * n) __builtin_amdgcn_s_sleep(1);
      }
      const int t = blk * 8 + tl;
      const float* gb = enc + ((size_t)t * 32 + row) * 512;
      float4 ba[8], bbf[8];
      #pragma unroll
      for (int p = 0; p < 8; ++p) {           // 16 independent loads in flight
        int G = g0 + 8 * p;
        ba[p]  = *(const float4*)(gb + G * 8);
        bbf[p] = *(const float4*)(gb + G * 8 + 4);
      }
      #pragma unroll
      for (int p = 0; p < 8; ++p) {
        int G = g0 + 8 * p;
        uint4 pk;
        pk.x = pack2(ba[p].x,  ba[p].y);
        pk.y = pack2(ba[p].z,  ba[p].w);
        pk.z = pack2(bbf[p].x, bbf[p].y);
        pk.w = pack2(bbf[p].z, bbf[p].w);
        *(uint4*)&As[s][row * 512 + (G ^ (row & 7)) * 8] = pk;  // verified swizzle
      }
      __threadfence_block();                  // ds_writes visible before flag
      if (lane == 0) atomicAdd(&fill[s], 1);
    }
  } else {
    // ---------------- consumers: waves 0-7 (n-slab w*64) ----------------
    const int quad = lane >> 4, col = lane & 15;
    const u16* bbase = W2bf + (size_t)w * 32768 + lane * 8;

    float uj[4], vj[4], rv[2][4][4];
    #pragma unroll
    for (int j = 0; j < 4; ++j) {
      int gh = w * 64 + j * 16 + col;
      uj[j] = u[gh];
      vj[j] = vv[gh];
    }
    #pragma unroll
    for (int i = 0; i < 2; ++i) {
      #pragma unroll
      for (int reg = 0; reg < 4; ++reg) {
        int bl = i * 16 + quad * 4 + reg;
        #pragma unroll
        for (int j = 0; j < 4; ++j)
          rv[i][reg][j] = r[bl * 512 + w * 64 + j * 16 + col];
      }
    }

    #pragma unroll 1
    for (int tl = 0; tl < 8; ++tl) {
      const int s = tl & 3, n = tl >> 2;
      const int t = blk * 8 + tl;
      while (vfill[s] < 4 * (n + 1)) __builtin_amdgcn_s_sleep(1);
      __threadfence_block();                  // acquire: no LDS-read hoist

      // K-loop: bf16 A from LDS slot, B 2-deep from L2. Verified r0 math.
      bf16x8 bb[2][4];
      #pragma unroll
      for (int j = 0; j < 4; ++j) {
        bb[0][j] = *(const bf16x8*)(bbase + j * 8192);
        bb[1][j] = *(const bf16x8*)(bbase + j * 8192 + 512);
      }
      f32x4 acc[2][4] = {};
      const u16* as = As[s];
      #pragma unroll
      for (int ks = 0; ks < 16; ++ks) {
        #pragma unroll
        for (int i = 0; i < 2; ++i) {
          int row = i * 16 + col;
          bf16x8 af = *(const bf16x8*)&as[row * 512 + ((ks * 4 + quad) ^ (col & 7)) * 8];
          #pragma unroll
          for (int j = 0; j < 4; ++j)
            acc[i][j] = __builtin_amdgcn_mfma_f32_16x16x32_bf16(af, bb[ks & 1][j], acc[i][j], 0, 0, 0);
        }
        if (ks < 14) {
          #pragma unroll
          for (int j = 0; j < 4; ++j)
            bb[ks & 1][j] = *(const bf16x8*)(bbase + j * 8192 + (ks + 2) * 512);
        }
      }

      // Epilogue: e = relu(acc + r + cov*u); partial = e·v over this wave's 64 h
      #pragma unroll
      for (int i = 0; i < 2; ++i) {
        #pragma unroll
        for (int reg = 0; reg < 4; ++reg) {
          int bl = i * 16 + quad * 4 + reg;    // C/D layout: row = quad*4 + reg
          float cv = cov[bl * 2048 + t];
          float sacc = 0.f;
          #pragma unroll
          for (int j = 0; j < 4; ++j) {
            float e = acc[i][j][reg] + rv[i][reg][j] + cv * uj[j];
            e = fmaxf(e, 0.f);
            sacc += e * vj[j];
          }
          sacc += __shfl_xor(sacc, 1);
          sacc += __shfl_xor(sacc, 2);
          sacc += __shfl_xor(sacc, 4);
          sacc += __shfl_xor(sacc, 8);
          if (col == 0) part[(size_t)(w * 32 + bl) * 2048 + t] = sacc;
        }
      }
      __threadfence_block();                  // slot reads complete before flag
      if (lane == 0) atomicAdd(&done[s], 1);
    }
  }
}

// Softmax over T per batch + coverage update. 32 blocks x 256 threads.
// part layout [p][b][t]: sum the 8 wave-partials (verified r0 path).
__global__ __launch_bounds__(256) void softmax_kernel(
    const float* __restrict__ part, const float* __restrict__ cov, float* __restrict__ out)
{
  const int b = blockIdx.x;
  const int tid = threadIdx.x;
  const int lane = tid & 63, wid = tid >> 6;
  __shared__ float red[4];
  float loc[8];
  float lmax = -3.4e38f;
  #pragma unroll
  for (int i = 0; i < 8; ++i) {
    int t = tid + i * 256;
    float s = 0.f;
    #pragma unroll
    for (int p = 0; p < 8; ++p) s += part[(size_t)(p * 32 + b) * 2048 + t];
    loc[i] = s;
    lmax = fmaxf(lmax, s);
  }
  #pragma unroll
  for (int o = 32; o; o >>= 1) lmax = fmaxf(lmax, __shfl_xor(lmax, o));
  if (lane == 0) red[wid] = lmax;
  __syncthreads();
  float bmax = fmaxf(fmaxf(red[0], red[1]), fmaxf(red[2], red[3]));
  __syncthreads();
  float lsum = 0.f;
  #pragma unroll
  for (int i = 0; i < 8; ++i) { loc[i] = __expf(loc[i] - bmax); lsum += loc[i]; }
  #pragma unroll
  for (int o = 32; o; o >>= 1) lsum += __shfl_xor(lsum, o);
  if (lane == 0) red[wid] = lsum;
  __syncthreads();
  float inv = 1.0f / (red[0] + red[1] + red[2] + red[3]);
  #pragma unroll
  for (int i = 0; i < 8; ++i) {
    int t = tid + i * 256;
    float a = loc[i] * inv;
    out[b * 2048 + t] = a;                               // attn_weights [B,1,T]
    out[65536 + b * 2048 + t] = cov[b * 2048 + t] + a;   // coverage_new [B,T]
  }
}

extern "C" void kernel_launch(void* const* d_in, const int* in_sizes, int n_in,
                              void* d_out, int out_size, void* d_ws, size_t ws_size,
                              hipStream_t stream) {
  const float* hidden = (const float*)d_in[0];   // [1,B,H]
  const float* enc    = (const float*)d_in[1];   // [T,B,H]
  const float* cov    = (const float*)d_in[2];   // [B,T]
  const float* W_attn = (const float*)d_in[3];   // [H,3H]
  const float* b_attn = (const float*)d_in[4];   // [H]
  const float* vv     = (const float*)d_in[5];   // [H]
  const float* W_cov  = (const float*)d_in[6];   // [H,1]
  float* out = (float*)d_out;

  u16* W2bf = (u16*)d_ws;                              // 512 KB (fragment-major)
  float* r  = (float*)((char*)d_ws + 512 * 1024);      // 64 KB
  float* u  = r + 32 * 512;                            // 2 KB
  float* part = u + 512;                               // 8 * 65536 * 4 = 2 MB

  hipLaunchKernelGGL(prep_kernel, dim3(256), dim3(256), 0, stream,
                     hidden, W_attn, b_attn, W_cov, W2bf, r, u);
  hipLaunchKernelGGL(gemm_score, dim3(256), dim3(768), 0, stream,
                     enc, W2bf, r, u, vv, cov, part);
  hipLaunchKernelGGL(softmax_kernel, dim3(32), dim3(256), 0, stream,
                     part, cov, out);
}